// Round 3
// baseline (501.564 us; speedup 1.0000x reference)
//
#include <hip/hip_runtime.h>
#include <hip/hip_bf16.h>
#include <cstdint>
#include <cstddef>

#define NB_B 8
#define NB_N 2048
#define NB_C 128
#define NB_H 4
#define NB_D 32
#define NB_S1 3
#define NB_K 16
#define NB_KT 48
#define INV_SQRT_D 0.17677669529663688f

// ---------------------------------------------------------------------------
// prep: sq[b,n] = |coord|^2  and  WkT[i][col][c] = Wk[i][c][col]
// ---------------------------------------------------------------------------
__global__ __launch_bounds__(256) void prep_kernel(const float* __restrict__ coord,
                                                   const float* __restrict__ Wk,
                                                   float* __restrict__ sq,
                                                   float* __restrict__ wkT) {
  int tid = blockIdx.x * 256 + threadIdx.x;
  if (tid < NB_B * NB_N) {
    float x = coord[tid * 3 + 0], y = coord[tid * 3 + 1], z = coord[tid * 3 + 2];
    sq[tid] = x * x + y * y + z * z;
  }
  if (tid < NB_S1 * NB_C * NB_C) {
    int i = tid >> 14;          // / 16384
    int rem = tid & 16383;
    int col = rem >> 7, c = rem & 127;
    wkT[tid] = Wk[i * 16384 + c * 128 + col];
  }
}

// ---------------------------------------------------------------------------
// topk2: ONE WAVE per point (frozen from round 2 — passed; rewrite next round)
// ---------------------------------------------------------------------------
__global__ __launch_bounds__(256) void topk2_kernel(const float* __restrict__ coord,
                                                    const float* __restrict__ sq,
                                                    int* __restrict__ idx_out) {
  const int t = threadIdx.x;
  const int w = t >> 6, l = t & 63;
  const int bn = blockIdx.x * 4 + w;          // one wave per point
  const int b = bn >> 11, n = bn & 2047;
  const float* cb = coord + (size_t)b * NB_N * 3;
  const float* sqb = sq + b * NB_N;

  const float cx = cb[n * 3 + 0], cy = cb[n * 3 + 1], cz = cb[n * 3 + 2];
  const float sqn = sqb[n];

  unsigned long long c0[8], c1[8], c2[8], c3[8];
#define DIST_KEY(dst, it)                                                     \
  {                                                                           \
    int m = (it) * 64 + l;                                                    \
    float mx = cb[m * 3 + 0], my = cb[m * 3 + 1], mz = cb[m * 3 + 2];         \
    float d = sqn + sqb[m] - 2.f * (cx * mx + cy * my + cz * mz);             \
    unsigned int db = __float_as_uint(d);                                     \
    unsigned int key = (db & 0x80000000u) ? ~db : (db | 0x80000000u);         \
    dst = ((unsigned long long)key << 32) | (unsigned int)m;                  \
  }
#pragma unroll
  for (int it = 0; it < 8; ++it) DIST_KEY(c0[it], it)
#pragma unroll
  for (int it = 0; it < 8; ++it) DIST_KEY(c1[it], 8 + it)
#pragma unroll
  for (int it = 0; it < 8; ++it) DIST_KEY(c2[it], 16 + it)
#pragma unroll
  for (int it = 0; it < 8; ++it) DIST_KEY(c3[it], 24 + it)
#undef DIST_KEY

#define CE(A, a, b)                                           \
  {                                                           \
    if (A[a] > A[b]) {                                        \
      unsigned long long tmp_ = A[a];                         \
      A[a] = A[b];                                            \
      A[b] = tmp_;                                            \
    }                                                         \
  }
#define SORT8(A)                                              \
  CE(A, 0, 1) CE(A, 2, 3) CE(A, 4, 5) CE(A, 6, 7)             \
  CE(A, 0, 2) CE(A, 1, 3) CE(A, 4, 6) CE(A, 5, 7)             \
  CE(A, 1, 2) CE(A, 5, 6)                                     \
  CE(A, 0, 4) CE(A, 1, 5) CE(A, 2, 6) CE(A, 3, 7)             \
  CE(A, 2, 4) CE(A, 3, 5)                                     \
  CE(A, 1, 2) CE(A, 3, 4) CE(A, 5, 6)
  SORT8(c0) SORT8(c1) SORT8(c2) SORT8(c3)
#undef SORT8
#undef CE

#define POP(A)                                                \
  {                                                           \
    A[0] = A[1]; A[1] = A[2]; A[2] = A[3]; A[3] = A[4];       \
    A[4] = A[5]; A[5] = A[6]; A[6] = A[7]; A[7] = ~0ULL;      \
  }

  unsigned long long lm;
  {
    unsigned long long a = c0[0] < c1[0] ? c0[0] : c1[0];
    unsigned long long b2 = c2[0] < c3[0] ? c2[0] : c3[0];
    lm = a < b2 ? a : b2;
  }

  unsigned int my_out = 0;
  for (int r = 0; r < NB_KT; ++r) {
    unsigned long long g = lm;
#pragma unroll
    for (int off = 1; off < 64; off <<= 1) {
      unsigned long long o = __shfl_xor(g, off);
      if (o < g) g = o;
    }
    if (l == r) my_out = (unsigned int)g;
    if (lm == g) {
      if (c0[0] == g) { POP(c0) }
      else if (c1[0] == g) { POP(c1) }
      else if (c2[0] == g) { POP(c2) }
      else { POP(c3) }
      unsigned long long a = c0[0] < c1[0] ? c0[0] : c1[0];
      unsigned long long b2 = c2[0] < c3[0] ? c2[0] : c3[0];
      lm = a < b2 ? a : b2;
    }
  }
#undef POP

  if (l < NB_KT) idx_out[(size_t)bn * NB_KT + l] = (int)my_out;
}

// ---------------------------------------------------------------------------
// async global->LDS, 16B per lane (dest = wave-uniform base + lane*16)
// ---------------------------------------------------------------------------
__device__ __forceinline__ void glds16(const float* src, float* dst) {
  __builtin_amdgcn_global_load_lds(
      (const __attribute__((address_space(1))) unsigned int*)src,
      (__attribute__((address_space(3))) unsigned int*)dst, 16, 0, 0);
}

// ---------------------------------------------------------------------------
// main fused kernel: 4 waves/block, 4 points/wave (16 points/block)
// lane layout: h_l = l>>4 (head), cg = l&15; lane's channels = {2cg+t+32s}
// ---------------------------------------------------------------------------
// stage 4 neighbor rows (unit K of group I, point P) into nbr_lds[w][SLOT]
#define STAGE(P, I, K, SLOT)                                                  \
  {                                                                           \
    int r0_ = __shfl(nidx[(P)], (I) * 16 + (K) * 4 + 0);                      \
    int r1_ = __shfl(nidx[(P)], (I) * 16 + (K) * 4 + 1);                      \
    int r2_ = __shfl(nidx[(P)], (I) * 16 + (K) * 4 + 2);                      \
    int r3_ = __shfl(nidx[(P)], (I) * 16 + (K) * 4 + 3);                      \
    glds16(pcd_b + (size_t)(l < 32 ? r0_ : r1_) * 128 + le,                   \
           &nbr_lds[w][(SLOT)][0][0]);                                        \
    glds16(pcd_b + (size_t)(l < 32 ? r2_ : r3_) * 128 + le,                   \
           &nbr_lds[w][(SLOT)][2][0]);                                        \
  }

__global__ __launch_bounds__(256) void main_kernel(
    const float* __restrict__ pcd,
    const float* __restrict__ Wq, const float* __restrict__ bq,
    const float* __restrict__ bk,
    const float* __restrict__ Wv, const float* __restrict__ bv,
    const float* __restrict__ wkT,
    const int* __restrict__ nbr_idx,
    float* __restrict__ out) {
  __shared__ __align__(16) float self_lds[16][128];       // 8 KB
  __shared__ float q_lds[16][132];                        // 8.25 KB (4 heads x 33)
  __shared__ float qbk_lds[16][12];                       // 768 B
  __shared__ __align__(16) float nbr_lds[4][2][4][128];   // 16 KB, per-wave dbuf

  const int t = threadIdx.x;
  const int w = t >> 6, l = t & 63;
  const int h_l = l >> 4, cg = l & 15;
  const int ws = w * 4;                     // wave's slot base (4 points)
  const int pt_base = blockIdx.x * 16 + ws;
  const int le = (l & 31) * 4;              // element offset within a row for glds
  const float* pcd_b = pcd + (size_t)((blockIdx.x * 16) >> 11) * NB_N * 128;

  // ---- stage self rows (wave-private slots) ----
#pragma unroll
  for (int p = 0; p < 4; ++p) {
    float2 s = reinterpret_cast<const float2*>(pcd + (size_t)(pt_base + p) * 128)[l];
    reinterpret_cast<float2*>(&self_lds[ws + p][0])[l] = s;
  }
  __syncthreads();

  // ---- q,v matvec: lane owns output cols 2l, 2l+1 for all 4 points ----
  float qa[4] = {0, 0, 0, 0}, qb[4] = {0, 0, 0, 0};
  float va[4] = {0, 0, 0, 0}, vb[4] = {0, 0, 0, 0};
#pragma unroll 4
  for (int c = 0; c < 128; ++c) {
    float2 wq = reinterpret_cast<const float2*>(Wq + c * 128)[l];
    float2 wv = reinterpret_cast<const float2*>(Wv + c * 128)[l];
#pragma unroll
    for (int p = 0; p < 4; ++p) {
      float x = self_lds[ws + p][c];
      qa[p] = fmaf(wq.x, x, qa[p]); qb[p] = fmaf(wq.y, x, qb[p]);
      va[p] = fmaf(wv.x, x, va[p]); vb[p] = fmaf(wv.y, x, vb[p]);
    }
  }
  {
    float2 bqv = reinterpret_cast<const float2*>(bq)[l];
    float2 bvv = reinterpret_cast<const float2*>(bv)[l];
#pragma unroll
    for (int p = 0; p < 4; ++p) {
      qa[p] += bqv.x; qb[p] += bqv.y; va[p] += bvv.x; vb[p] += bvv.y;
    }
  }
#pragma unroll
  for (int p = 0; p < 4; ++p) {
    q_lds[ws + p][h_l * 33 + 2 * cg] = qa[p];
    q_lds[ws + p][h_l * 33 + 2 * cg + 1] = qb[p];
  }
  // qbk[p][i][h] = q[h,:] . bk[i][h*32:...]  (wave-private q_lds)
  if (l < 48) {
    int p = l / 12, g = l % 12;
    int i = g >> 2, h = g & 3;
    const float* qp = &q_lds[ws + p][h * 33];
    const float* bkp = bk + i * 128 + h * 32;
    float s = 0.f;
#pragma unroll 8
    for (int d = 0; d < 32; ++d) s = fmaf(qp[d], bkp[d], s);
    qbk_lds[ws + p][g] = s;
  }
  __syncthreads();

  int nidx[4];
#pragma unroll
  for (int p = 0; p < 4; ++p)
    nidx[p] = (l < 48) ? nbr_idx[(size_t)(pt_base + p) * NB_KT + l] : 0;

  float am[4] = {0, 0, 0, 0};

#pragma unroll
  for (int i = 0; i < 3; ++i) {
    // ---- u[p][2s+t] = sum_d wkT[i][h_l*32+d][2cg+t+32s] * q_p[h_l,d] ----
    float u[4][8];
#pragma unroll
    for (int p = 0; p < 4; ++p)
#pragma unroll
      for (int k = 0; k < 8; ++k) u[p][k] = 0.f;
    {
      const float* wrow = wkT + i * 16384 + (h_l * 32) * 128 + 2 * cg;
#pragma unroll 4
      for (int d = 0; d < 32; ++d) {
        float qv[4];
#pragma unroll
        for (int p = 0; p < 4; ++p) qv[p] = q_lds[ws + p][h_l * 33 + d];
#pragma unroll
        for (int s = 0; s < 4; ++s) {
          float2 w2 = *reinterpret_cast<const float2*>(wrow + d * 128 + 32 * s);
#pragma unroll
          for (int p = 0; p < 4; ++p) {
            u[p][2 * s]     = fmaf(w2.x, qv[p], u[p][2 * s]);
            u[p][2 * s + 1] = fmaf(w2.y, qv[p], u[p][2 * s + 1]);
          }
        }
      }
    }
    // ---- base[p] = qbk[p][i][h_l] - sum_c self[c]*u[c]  (per 16-lane group) --
    float base[4];
#pragma unroll
    for (int p = 0; p < 4; ++p) {
      float sd = 0.f;
#pragma unroll
      for (int s = 0; s < 4; ++s) {
        float2 c2 = *reinterpret_cast<const float2*>(&self_lds[ws + p][2 * cg + 32 * s]);
        sd = fmaf(c2.x, u[p][2 * s], sd);
        sd = fmaf(c2.y, u[p][2 * s + 1], sd);
      }
      sd += __shfl_xor(sd, 1);
      sd += __shfl_xor(sd, 2);
      sd += __shfl_xor(sd, 4);
      sd += __shfl_xor(sd, 8);
      base[p] = qbk_lds[ws + p][i * 4 + h_l] - sd;
    }
    // ---- logits (4 units of 4 rows, dbuf, counted vmcnt) + softmax ----
#pragma unroll
    for (int p = 0; p < 4; ++p) {
      STAGE(p, i, 0, 0)
      float myl = 0.f;
#pragma unroll
      for (int k = 0; k < 4; ++k) {
        if (k < 3) {
          STAGE(p, i, k + 1, (k + 1) & 1)
          asm volatile("s_waitcnt vmcnt(2)" ::: "memory");
        } else {
          asm volatile("s_waitcnt vmcnt(0)" ::: "memory");
        }
#pragma unroll
        for (int jj = 0; jj < 4; ++jj) {
          const float* row = &nbr_lds[w][k & 1][jj][0];
          float2 n0 = *reinterpret_cast<const float2*>(row + 2 * cg);
          float2 n1 = *reinterpret_cast<const float2*>(row + 2 * cg + 32);
          float2 n2 = *reinterpret_cast<const float2*>(row + 2 * cg + 64);
          float2 n3 = *reinterpret_cast<const float2*>(row + 2 * cg + 96);
          float pd;
          pd = n0.x * u[p][0];
          pd = fmaf(n0.y, u[p][1], pd);
          pd = fmaf(n1.x, u[p][2], pd);
          pd = fmaf(n1.y, u[p][3], pd);
          pd = fmaf(n2.x, u[p][4], pd);
          pd = fmaf(n2.y, u[p][5], pd);
          pd = fmaf(n3.x, u[p][6], pd);
          pd = fmaf(n3.y, u[p][7], pd);
          pd += __shfl_xor(pd, 1);
          pd += __shfl_xor(pd, 2);
          pd += __shfl_xor(pd, 4);
          pd += __shfl_xor(pd, 8);
          float lg = (pd + base[p]) * INV_SQRT_D;
          if (cg == 4 * k + jj) myl = lg;
        }
      }
      // softmax over the 16 lanes of this head group
      float m = myl;
      m = fmaxf(m, __shfl_xor(m, 1));
      m = fmaxf(m, __shfl_xor(m, 2));
      m = fmaxf(m, __shfl_xor(m, 4));
      m = fmaxf(m, __shfl_xor(m, 8));
      float e = expf(myl - m);
      float se = e, swl = e * myl;
      se += __shfl_xor(se, 1); swl += __shfl_xor(swl, 1);
      se += __shfl_xor(se, 2); swl += __shfl_xor(swl, 2);
      se += __shfl_xor(se, 4); swl += __shfl_xor(swl, 4);
      se += __shfl_xor(se, 8); swl += __shfl_xor(swl, 8);
      am[p] += swl / se;
    }
  }

  // ---- epilogue: out[pt_p, 2l+{0,1}] = attn[h_l] * v ----
#pragma unroll
  for (int p = 0; p < 4; ++p) {
    float2 o = make_float2(am[p] * va[p], am[p] * vb[p]);
    reinterpret_cast<float2*>(out + (size_t)(pt_base + p) * 128)[l] = o;
  }
}

// ---------------------------------------------------------------------------
extern "C" void kernel_launch(void* const* d_in, const int* in_sizes, int n_in,
                              void* d_out, int out_size, void* d_ws, size_t ws_size,
                              hipStream_t stream) {
  const float* pcd   = (const float*)d_in[0];
  const float* coord = (const float*)d_in[1];
  // d_in[2] = K (scalar int, fixed 16 — hardcoded)
  const float* Wq = (const float*)d_in[3];
  const float* bq = (const float*)d_in[4];
  const float* Wk = (const float*)d_in[5];
  const float* bk = (const float*)d_in[6];
  const float* Wv = (const float*)d_in[7];
  const float* bv = (const float*)d_in[8];
  float* out = (float*)d_out;

  // workspace layout
  int*   idx_ws = (int*)d_ws;                                   // 16384*48*4 = 3,145,728 B
  float* sq_ws  = (float*)((char*)d_ws + 3145728);              // 65,536 B
  float* wkT_ws = (float*)((char*)d_ws + 3211264);              // 196,608 B

  prep_kernel<<<192, 256, 0, stream>>>(coord, Wk, sq_ws, wkT_ws);
  topk2_kernel<<<NB_B * NB_N / 4, 256, 0, stream>>>(coord, sq_ws, idx_ws);
  main_kernel<<<NB_B * NB_N / 16, 256, 0, stream>>>(pcd, Wq, bq, bk, Wv, bv,
                                                    wkT_ws, idx_ws, out);
}

// Round 4
// 350.607 us; speedup vs baseline: 1.4306x; 1.4306x over previous
//
#include <hip/hip_runtime.h>
#include <hip/hip_bf16.h>
#include <cstdint>
#include <cstddef>

#define NB_B 8
#define NB_N 2048
#define NB_C 128
#define NB_H 4
#define NB_D 32
#define NB_S1 3
#define NB_K 16
#define NB_KT 48
#define INV_SQRT_D 0.17677669529663688f

// ---- DPP reduce helpers: 16-lane group reduce, all-VALU (no DS ops) -------
// span{1,2,7,15} = {0..15}: xor1=quad_perm[1,0,3,2](0xB1), xor2=quad_perm
// [2,3,0,1](0x4E), xor7=row_half_mirror(0x141), xor15=row_mirror(0x140).
#define DPP_F(x, ctrl) \
  __int_as_float(__builtin_amdgcn_update_dpp(0, __float_as_int(x), ctrl, 0xF, 0xF, true))

__device__ __forceinline__ float sum16(float x) {
  x += DPP_F(x, 0xB1);
  x += DPP_F(x, 0x4E);
  x += DPP_F(x, 0x141);
  x += DPP_F(x, 0x140);
  return x;
}
__device__ __forceinline__ float max16(float x) {
  x = fmaxf(x, DPP_F(x, 0xB1));
  x = fmaxf(x, DPP_F(x, 0x4E));
  x = fmaxf(x, DPP_F(x, 0x141));
  x = fmaxf(x, DPP_F(x, 0x140));
  return x;
}

// u64 min step with DPP'd partner (within 16-lane rows)
#define DPP_MIN64(g, ctrl)                                                        \
  {                                                                               \
    unsigned int lo_ = (unsigned int)(g), hi_ = (unsigned int)((g) >> 32);        \
    unsigned int l2_ =                                                            \
        (unsigned int)__builtin_amdgcn_update_dpp(0, (int)lo_, ctrl, 0xF, 0xF, true); \
    unsigned int h2_ =                                                            \
        (unsigned int)__builtin_amdgcn_update_dpp(0, (int)hi_, ctrl, 0xF, 0xF, true); \
    unsigned long long o_ = ((unsigned long long)h2_ << 32) | l2_;                \
    if (o_ < (g)) (g) = o_;                                                       \
  }

// ---------------------------------------------------------------------------
// prep: sq[b,n] = |coord|^2  and  WkT[i][col][c] = Wk[i][c][col]
// ---------------------------------------------------------------------------
__global__ __launch_bounds__(256) void prep_kernel(const float* __restrict__ coord,
                                                   const float* __restrict__ Wk,
                                                   float* __restrict__ sq,
                                                   float* __restrict__ wkT) {
  int tid = blockIdx.x * 256 + threadIdx.x;
  if (tid < NB_B * NB_N) {
    float x = coord[tid * 3 + 0], y = coord[tid * 3 + 1], z = coord[tid * 3 + 2];
    sq[tid] = x * x + y * y + z * z;
  }
  if (tid < NB_S1 * NB_C * NB_C) {
    int i = tid >> 14;          // / 16384
    int rem = tid & 16383;
    int col = rem >> 7, c = rem & 127;
    wkT[tid] = Wk[i * 16384 + c * 128 + col];
  }
}

// ---------------------------------------------------------------------------
// topk2: ONE WAVE per point. 48 extraction rounds; wave-min via DPP (4 VALU
// hops) + shfl xor16/xor32 (2 DS hops). Exact (dist,idx) lexicographic order.
// ---------------------------------------------------------------------------
__global__ __launch_bounds__(256) void topk2_kernel(const float* __restrict__ coord,
                                                    const float* __restrict__ sq,
                                                    int* __restrict__ idx_out) {
  const int t = threadIdx.x;
  const int w = t >> 6, l = t & 63;
  const int bn = blockIdx.x * 4 + w;          // one wave per point
  const int b = bn >> 11, n = bn & 2047;
  const float* cb = coord + (size_t)b * NB_N * 3;
  const float* sqb = sq + b * NB_N;

  const float cx = cb[n * 3 + 0], cy = cb[n * 3 + 1], cz = cb[n * 3 + 2];
  const float sqn = sqb[n];

  unsigned long long c0[8], c1[8], c2[8], c3[8];
#define DIST_KEY(dst, it)                                                     \
  {                                                                           \
    int m = (it) * 64 + l;                                                    \
    float mx = cb[m * 3 + 0], my = cb[m * 3 + 1], mz = cb[m * 3 + 2];         \
    float d = sqn + sqb[m] - 2.f * (cx * mx + cy * my + cz * mz);             \
    unsigned int db = __float_as_uint(d);                                     \
    unsigned int key = (db & 0x80000000u) ? ~db : (db | 0x80000000u);         \
    dst = ((unsigned long long)key << 32) | (unsigned int)m;                  \
  }
#pragma unroll
  for (int it = 0; it < 8; ++it) DIST_KEY(c0[it], it)
#pragma unroll
  for (int it = 0; it < 8; ++it) DIST_KEY(c1[it], 8 + it)
#pragma unroll
  for (int it = 0; it < 8; ++it) DIST_KEY(c2[it], 16 + it)
#pragma unroll
  for (int it = 0; it < 8; ++it) DIST_KEY(c3[it], 24 + it)
#undef DIST_KEY

#define CE(A, a, b)                                           \
  {                                                           \
    if (A[a] > A[b]) {                                        \
      unsigned long long tmp_ = A[a];                         \
      A[a] = A[b];                                            \
      A[b] = tmp_;                                            \
    }                                                         \
  }
#define SORT8(A)                                              \
  CE(A, 0, 1) CE(A, 2, 3) CE(A, 4, 5) CE(A, 6, 7)             \
  CE(A, 0, 2) CE(A, 1, 3) CE(A, 4, 6) CE(A, 5, 7)             \
  CE(A, 1, 2) CE(A, 5, 6)                                     \
  CE(A, 0, 4) CE(A, 1, 5) CE(A, 2, 6) CE(A, 3, 7)             \
  CE(A, 2, 4) CE(A, 3, 5)                                     \
  CE(A, 1, 2) CE(A, 3, 4) CE(A, 5, 6)
  SORT8(c0) SORT8(c1) SORT8(c2) SORT8(c3)
#undef SORT8
#undef CE

#define POP(A)                                                \
  {                                                           \
    A[0] = A[1]; A[1] = A[2]; A[2] = A[3]; A[3] = A[4];       \
    A[4] = A[5]; A[5] = A[6]; A[6] = A[7]; A[7] = ~0ULL;      \
  }

  unsigned long long lm;
  {
    unsigned long long a = c0[0] < c1[0] ? c0[0] : c1[0];
    unsigned long long b2 = c2[0] < c3[0] ? c2[0] : c3[0];
    lm = a < b2 ? a : b2;
  }

  unsigned int my_out = 0;
  for (int r = 0; r < NB_KT; ++r) {
    // wave-wide u64 min: 4 DPP hops (VALU) + xor16 + xor32 shuffles
    unsigned long long g = lm;
    DPP_MIN64(g, 0xB1)
    DPP_MIN64(g, 0x4E)
    DPP_MIN64(g, 0x141)
    DPP_MIN64(g, 0x140)
    {
      unsigned long long o = __shfl_xor(g, 16);
      if (o < g) g = o;
    }
    {
      unsigned long long o = __shfl_xor(g, 32);
      if (o < g) g = o;
    }
    if (l == r) my_out = (unsigned int)g;
    if (lm == g) {                          // unique winning lane pops
      if (c0[0] == g) { POP(c0) }
      else if (c1[0] == g) { POP(c1) }
      else if (c2[0] == g) { POP(c2) }
      else { POP(c3) }
      unsigned long long a = c0[0] < c1[0] ? c0[0] : c1[0];
      unsigned long long b2 = c2[0] < c3[0] ? c2[0] : c3[0];
      lm = a < b2 ? a : b2;
    }
  }
#undef POP

  if (l < NB_KT) idx_out[(size_t)bn * NB_KT + l] = (int)my_out;
}

// ---------------------------------------------------------------------------
// main fused kernel: 4 waves/block, 4 points/wave (16 points/block)
// lane layout: h_l = l>>4 (head), cg = l&15; lane owns channels
// {4cg..4cg+3} and {64+4cg..64+4cg+3}. Neighbor rows loaded DIRECTLY from
// global to registers (SGPR row base via readlane, 2x dwordx4 per row).
// All LDS is wave-private: no barriers.
// ---------------------------------------------------------------------------
__global__ __launch_bounds__(256) void main_kernel(
    const float* __restrict__ pcd,
    const float* __restrict__ Wq, const float* __restrict__ bq,
    const float* __restrict__ bk,
    const float* __restrict__ Wv, const float* __restrict__ bv,
    const float* __restrict__ wkT,
    const int* __restrict__ nbr_idx,
    float* __restrict__ out) {
  __shared__ __align__(16) float self_lds[16][128];       // 8 KB
  __shared__ float q_lds[16][132];                        // 8.25 KB (4 heads x 33)
  __shared__ float qbk_lds[16][12];                       // 768 B

  const int t = threadIdx.x;
  const int w = t >> 6, l = t & 63;
  const int h_l = l >> 4, cg = l & 15;
  const int ws = w * 4;                     // wave's slot base (4 points)
  const int pt_base = blockIdx.x * 16 + ws;
  const float* pcd_b = pcd + (size_t)((blockIdx.x * 16) >> 11) * NB_N * 128;

  // ---- stage self rows (wave-private slots; same-wave LDS ordering) ----
#pragma unroll
  for (int p = 0; p < 4; ++p) {
    float2 s = reinterpret_cast<const float2*>(pcd + (size_t)(pt_base + p) * 128)[l];
    reinterpret_cast<float2*>(&self_lds[ws + p][0])[l] = s;
  }

  // ---- q,v matvec: lane owns output cols 2l, 2l+1 for all 4 points ----
  float qa[4] = {0, 0, 0, 0}, qb[4] = {0, 0, 0, 0};
  float va[4] = {0, 0, 0, 0}, vb[4] = {0, 0, 0, 0};
#pragma unroll 4
  for (int c = 0; c < 128; ++c) {
    float2 wq = reinterpret_cast<const float2*>(Wq + c * 128)[l];
    float2 wv = reinterpret_cast<const float2*>(Wv + c * 128)[l];
#pragma unroll
    for (int p = 0; p < 4; ++p) {
      float x = self_lds[ws + p][c];
      qa[p] = fmaf(wq.x, x, qa[p]); qb[p] = fmaf(wq.y, x, qb[p]);
      va[p] = fmaf(wv.x, x, va[p]); vb[p] = fmaf(wv.y, x, vb[p]);
    }
  }
  {
    float2 bqv = reinterpret_cast<const float2*>(bq)[l];
    float2 bvv = reinterpret_cast<const float2*>(bv)[l];
#pragma unroll
    for (int p = 0; p < 4; ++p) {
      qa[p] += bqv.x; qb[p] += bqv.y; va[p] += bvv.x; vb[p] += bvv.y;
    }
  }
#pragma unroll
  for (int p = 0; p < 4; ++p) {
    int hh = l >> 4;
    q_lds[ws + p][hh * 33 + 2 * cg] = qa[p];
    q_lds[ws + p][hh * 33 + 2 * cg + 1] = qb[p];
  }
  // qbk[p][i][h] = q[h,:] . bk[i][h*32:...]  (wave-private)
  if (l < 48) {
    int p = l / 12, g = l % 12;
    int i = g >> 2, h = g & 3;
    const float* qp = &q_lds[ws + p][h * 33];
    const float* bkp = bk + i * 128 + h * 32;
    float s = 0.f;
#pragma unroll 8
    for (int d = 0; d < 32; ++d) s = fmaf(qp[d], bkp[d], s);
    qbk_lds[ws + p][g] = s;
  }

  int nidx[4];
#pragma unroll
  for (int p = 0; p < 4; ++p)
    nidx[p] = (l < 48) ? nbr_idx[(size_t)(pt_base + p) * NB_KT + l] : 0;

  float am[4] = {0, 0, 0, 0};

#pragma unroll
  for (int i = 0; i < 3; ++i) {
    // ---- u[p][t] ~ channel 4cg+t (t<4), 64+4cg+(t-4) (t>=4) ----
    float u[4][8];
#pragma unroll
    for (int p = 0; p < 4; ++p)
#pragma unroll
      for (int k = 0; k < 8; ++k) u[p][k] = 0.f;
    {
      const float* wrow = wkT + i * 16384 + (h_l * 32) * 128 + 4 * cg;
#pragma unroll 4
      for (int d = 0; d < 32; ++d) {
        float4 wa = *reinterpret_cast<const float4*>(wrow + d * 128);
        float4 wb = *reinterpret_cast<const float4*>(wrow + d * 128 + 64);
        float qv[4];
#pragma unroll
        for (int p = 0; p < 4; ++p) qv[p] = q_lds[ws + p][h_l * 33 + d];
#pragma unroll
        for (int p = 0; p < 4; ++p) {
          u[p][0] = fmaf(wa.x, qv[p], u[p][0]);
          u[p][1] = fmaf(wa.y, qv[p], u[p][1]);
          u[p][2] = fmaf(wa.z, qv[p], u[p][2]);
          u[p][3] = fmaf(wa.w, qv[p], u[p][3]);
          u[p][4] = fmaf(wb.x, qv[p], u[p][4]);
          u[p][5] = fmaf(wb.y, qv[p], u[p][5]);
          u[p][6] = fmaf(wb.z, qv[p], u[p][6]);
          u[p][7] = fmaf(wb.w, qv[p], u[p][7]);
        }
      }
    }
    // ---- base[p] = qbk[p][i][h_l] - sum_c self[c]*u[c] ----
    float base[4];
#pragma unroll
    for (int p = 0; p < 4; ++p) {
      const float4* sp = reinterpret_cast<const float4*>(&self_lds[ws + p][4 * cg]);
      float4 sA = sp[0];
      float4 sB = sp[16];   // +64 floats
      float sd;
      sd = sA.x * u[p][0];
      sd = fmaf(sA.y, u[p][1], sd);
      sd = fmaf(sA.z, u[p][2], sd);
      sd = fmaf(sA.w, u[p][3], sd);
      sd = fmaf(sB.x, u[p][4], sd);
      sd = fmaf(sB.y, u[p][5], sd);
      sd = fmaf(sB.z, u[p][6], sd);
      sd = fmaf(sB.w, u[p][7], sd);
      sd = sum16(sd);
      base[p] = qbk_lds[ws + p][i * 4 + h_l] - sd;
    }
    // ---- logits: 16 neighbor rows direct global->reg, fully unrolled ----
#pragma unroll
    for (int p = 0; p < 4; ++p) {
      float myl = 0.f;
#pragma unroll
      for (int j = 0; j < 16; ++j) {
        int nb = __builtin_amdgcn_readlane(nidx[p], i * 16 + j);  // uniform -> SGPR
        const float* rowp = pcd_b + (size_t)(unsigned)nb * 128 + 4 * cg;
        float4 nA = *reinterpret_cast<const float4*>(rowp);
        float4 nB = *reinterpret_cast<const float4*>(rowp + 64);
        float pd;
        pd = nA.x * u[p][0];
        pd = fmaf(nA.y, u[p][1], pd);
        pd = fmaf(nA.z, u[p][2], pd);
        pd = fmaf(nA.w, u[p][3], pd);
        pd = fmaf(nB.x, u[p][4], pd);
        pd = fmaf(nB.y, u[p][5], pd);
        pd = fmaf(nB.z, u[p][6], pd);
        pd = fmaf(nB.w, u[p][7], pd);
        pd = sum16(pd);
        float lg = (pd + base[p]) * INV_SQRT_D;
        if (cg == j) myl = lg;
      }
      // softmax over the 16 lanes of this head group (all-VALU DPP)
      float m = max16(myl);
      float e = expf(myl - m);
      float swl = e * myl;
      float se = sum16(e);
      swl = sum16(swl);
      am[p] += swl / se;
    }
  }

  // ---- epilogue: out[pt_p, 2l+{0,1}] = attn[h_l] * v ----
#pragma unroll
  for (int p = 0; p < 4; ++p) {
    float2 o = make_float2(am[p] * va[p], am[p] * vb[p]);
    reinterpret_cast<float2*>(out + (size_t)(pt_base + p) * 128)[l] = o;
  }
}

// ---------------------------------------------------------------------------
extern "C" void kernel_launch(void* const* d_in, const int* in_sizes, int n_in,
                              void* d_out, int out_size, void* d_ws, size_t ws_size,
                              hipStream_t stream) {
  const float* pcd   = (const float*)d_in[0];
  const float* coord = (const float*)d_in[1];
  // d_in[2] = K (scalar int, fixed 16 — hardcoded)
  const float* Wq = (const float*)d_in[3];
  const float* bq = (const float*)d_in[4];
  const float* Wk = (const float*)d_in[5];
  const float* bk = (const float*)d_in[6];
  const float* Wv = (const float*)d_in[7];
  const float* bv = (const float*)d_in[8];
  float* out = (float*)d_out;

  // workspace layout
  int*   idx_ws = (int*)d_ws;                                   // 16384*48*4 = 3,145,728 B
  float* sq_ws  = (float*)((char*)d_ws + 3145728);              // 65,536 B
  float* wkT_ws = (float*)((char*)d_ws + 3211264);              // 196,608 B

  prep_kernel<<<192, 256, 0, stream>>>(coord, Wk, sq_ws, wkT_ws);
  topk2_kernel<<<NB_B * NB_N / 4, 256, 0, stream>>>(coord, sq_ws, idx_ws);
  main_kernel<<<NB_B * NB_N / 16, 256, 0, stream>>>(pcd, Wq, bq, bk, Wv, bv,
                                                    wkT_ws, idx_ws, out);
}

// Round 5
// 280.797 us; speedup vs baseline: 1.7862x; 1.2486x over previous
//
#include <hip/hip_runtime.h>
#include <hip/hip_bf16.h>
#include <cstdint>
#include <cstddef>

#define NB_B 8
#define NB_N 2048
#define NB_C 128
#define NB_H 4
#define NB_D 32
#define NB_S1 3
#define NB_K 16
#define NB_KT 48
#define INV_SQRT_D 0.17677669529663688f

// ---- DPP reduce helpers: 16-lane group reduce, all-VALU (no DS ops) -------
#define DPP_F(x, ctrl) \
  __int_as_float(__builtin_amdgcn_update_dpp(0, __float_as_int(x), ctrl, 0xF, 0xF, true))

__device__ __forceinline__ float sum16(float x) {
  x += DPP_F(x, 0xB1);
  x += DPP_F(x, 0x4E);
  x += DPP_F(x, 0x141);
  x += DPP_F(x, 0x140);
  return x;
}
__device__ __forceinline__ float max16(float x) {
  x = fmaxf(x, DPP_F(x, 0xB1));
  x = fmaxf(x, DPP_F(x, 0x4E));
  x = fmaxf(x, DPP_F(x, 0x141));
  x = fmaxf(x, DPP_F(x, 0x140));
  return x;
}

// u64 min step with DPP'd partner (within 16-lane rows) — used by fallback
#define DPP_MIN64(g, ctrl)                                                        \
  {                                                                               \
    unsigned int lo_ = (unsigned int)(g), hi_ = (unsigned int)((g) >> 32);        \
    unsigned int l2_ =                                                            \
        (unsigned int)__builtin_amdgcn_update_dpp(0, (int)lo_, ctrl, 0xF, 0xF, true); \
    unsigned int h2_ =                                                            \
        (unsigned int)__builtin_amdgcn_update_dpp(0, (int)hi_, ctrl, 0xF, 0xF, true); \
    unsigned long long o_ = ((unsigned long long)h2_ << 32) | l2_;                \
    if (o_ < (g)) (g) = o_;                                                       \
  }

__device__ __forceinline__ unsigned long long u64min(unsigned long long a,
                                                     unsigned long long b) {
  return a < b ? a : b;
}
__device__ __forceinline__ unsigned long long u64max(unsigned long long a,
                                                     unsigned long long b) {
  return a > b ? a : b;
}

// Canonical bitonic sort of 128 u64 across a wave (2 elements/lane,
// global index = 2*lane + r), ascending. 28 steps: 7 in-lane, 21 cross-lane.
__device__ __forceinline__ void bitonic128(unsigned long long& v0,
                                           unsigned long long& v1, int L) {
#pragma unroll
  for (int k = 2; k <= 128; k <<= 1) {
#pragma unroll
    for (int j = k >> 1; j > 0; j >>= 1) {
      bool up = ((L & (k >> 1)) == 0);
      if (j == 1) {
        unsigned long long lo = u64min(v0, v1), hi = u64max(v0, v1);
        v0 = up ? lo : hi;
        v1 = up ? hi : lo;
      } else {
        int lx = j >> 1;
        unsigned long long o0 = __shfl_xor(v0, lx);
        unsigned long long o1 = __shfl_xor(v1, lx);
        bool keepmin = (((L & lx) == 0) == up);
        v0 = keepmin ? u64min(v0, o0) : u64max(v0, o0);
        v1 = keepmin ? u64min(v1, o1) : u64max(v1, o1);
      }
    }
  }
}

// bottom-2 of the union of two sorted pairs (a0<=a1, b0<=b1)
#define BOT2(r0, r1, a0, a1, b0, b1)                          \
  {                                                           \
    r0 = u64min(a0, b0);                                      \
    r1 = u64min(u64max(a0, b0), (a0 < b0) ? (a1) : (b1));     \
  }

// ---------------------------------------------------------------------------
// prep: sq[b,n] = |coord|^2  and  WkT[i][col][c] = Wk[i][c][col]
// ---------------------------------------------------------------------------
__global__ __launch_bounds__(256) void prep_kernel(const float* __restrict__ coord,
                                                   const float* __restrict__ Wk,
                                                   float* __restrict__ sq,
                                                   float* __restrict__ wkT) {
  int tid = blockIdx.x * 256 + threadIdx.x;
  if (tid < NB_B * NB_N) {
    float x = coord[tid * 3 + 0], y = coord[tid * 3 + 1], z = coord[tid * 3 + 2];
    sq[tid] = x * x + y * y + z * z;
  }
  if (tid < NB_S1 * NB_C * NB_C) {
    int i = tid >> 14;          // / 16384
    int rem = tid & 16383;
    int col = rem >> 7, c = rem & 127;
    wkT[tid] = Wk[i * 16384 + c * 128 + col];
  }
}

// ---------------------------------------------------------------------------
// topk3: ONE WAVE per point. Exact top-48 by (dist,idx) via:
//  1) per-lane 32 keys in 4 sorted-8 lists (as before)
//  2) T = 48th smallest of the 128 per-lane-top-2 samples (bitonic128)
//     -> provable upper bound on the 48th-smallest global key
//  3) compact all candidates <= T to LDS (wave prefix scan), pad to 128
//  4) bitonic128 over survivors -> first 48 are exact, sorted
//  5) fallback to serial 48-round extraction if survivors > 128 (pathological)
// ---------------------------------------------------------------------------
__global__ __launch_bounds__(256) void topk3_kernel(const float* __restrict__ coord,
                                                    const float* __restrict__ sq,
                                                    int* __restrict__ idx_out) {
  __shared__ unsigned long long srv[4][128];   // per-wave survivor buffer (4 KB)
  const int t = threadIdx.x;
  const int w = t >> 6, l = t & 63;
  const int bn = blockIdx.x * 4 + w;          // one wave per point
  const int b = bn >> 11, n = bn & 2047;
  const float* cb = coord + (size_t)b * NB_N * 3;
  const float* sqb = sq + b * NB_N;

  const float cx = cb[n * 3 + 0], cy = cb[n * 3 + 1], cz = cb[n * 3 + 2];
  const float sqn = sqb[n];

  unsigned long long c0[8], c1[8], c2[8], c3[8];
#define DIST_KEY(dst, it)                                                     \
  {                                                                           \
    int m = (it) * 64 + l;                                                    \
    float mx = cb[m * 3 + 0], my = cb[m * 3 + 1], mz = cb[m * 3 + 2];         \
    float d = sqn + sqb[m] - 2.f * (cx * mx + cy * my + cz * mz);             \
    unsigned int db = __float_as_uint(d);                                     \
    unsigned int key = (db & 0x80000000u) ? ~db : (db | 0x80000000u);         \
    dst = ((unsigned long long)key << 32) | (unsigned int)m;                  \
  }
#pragma unroll
  for (int it = 0; it < 8; ++it) DIST_KEY(c0[it], it)
#pragma unroll
  for (int it = 0; it < 8; ++it) DIST_KEY(c1[it], 8 + it)
#pragma unroll
  for (int it = 0; it < 8; ++it) DIST_KEY(c2[it], 16 + it)
#pragma unroll
  for (int it = 0; it < 8; ++it) DIST_KEY(c3[it], 24 + it)
#undef DIST_KEY

#define CE(A, a, b)                                           \
  {                                                           \
    if (A[a] > A[b]) {                                        \
      unsigned long long tmp_ = A[a];                         \
      A[a] = A[b];                                            \
      A[b] = tmp_;                                            \
    }                                                         \
  }
#define SORT8(A)                                              \
  CE(A, 0, 1) CE(A, 2, 3) CE(A, 4, 5) CE(A, 6, 7)             \
  CE(A, 0, 2) CE(A, 1, 3) CE(A, 4, 6) CE(A, 5, 7)             \
  CE(A, 1, 2) CE(A, 5, 6)                                     \
  CE(A, 0, 4) CE(A, 1, 5) CE(A, 2, 6) CE(A, 3, 7)             \
  CE(A, 2, 4) CE(A, 3, 5)                                     \
  CE(A, 1, 2) CE(A, 3, 4) CE(A, 5, 6)
  SORT8(c0) SORT8(c1) SORT8(c2) SORT8(c3)
#undef SORT8
#undef CE

  // ---- per-lane two smallest (lists are sorted -> among first two of each) --
  unsigned long long x0, x1, y0, y1, m1, m2;
  BOT2(x0, x1, c0[0], c0[1], c1[0], c1[1])
  BOT2(y0, y1, c2[0], c2[1], c3[0], c3[1])
  BOT2(m1, m2, x0, x1, y0, y1)

  // ---- T = 48th smallest of the 128 samples ----
  unsigned long long v0 = m1, v1 = m2;
  bitonic128(v0, v1, l);
  const unsigned long long T = __shfl(v1, 23);   // global element #47

  // ---- count candidates <= T, wave prefix scan ----
  int cnt = 0;
#pragma unroll
  for (int j = 0; j < 8; ++j) cnt += (c0[j] <= T) ? 1 : 0;
#pragma unroll
  for (int j = 0; j < 8; ++j) cnt += (c1[j] <= T) ? 1 : 0;
#pragma unroll
  for (int j = 0; j < 8; ++j) cnt += (c2[j] <= T) ? 1 : 0;
#pragma unroll
  for (int j = 0; j < 8; ++j) cnt += (c3[j] <= T) ? 1 : 0;
  int inc = cnt;
#pragma unroll
  for (int off = 1; off < 64; off <<= 1) {
    int y = __shfl_up(inc, off);
    if (l >= off) inc += y;
  }
  const int M = __shfl(inc, 63);
  const int excl = inc - cnt;

  if (M <= 128) {
    // pad, then scatter survivors (DS pipe is in-order per wave)
    srv[w][l] = ~0ULL;
    srv[w][l + 64] = ~0ULL;
    int k = excl;
#pragma unroll
    for (int j = 0; j < 8; ++j)
      if (c0[j] <= T) { srv[w][k] = c0[j]; ++k; }
#pragma unroll
    for (int j = 0; j < 8; ++j)
      if (c1[j] <= T) { srv[w][k] = c1[j]; ++k; }
#pragma unroll
    for (int j = 0; j < 8; ++j)
      if (c2[j] <= T) { srv[w][k] = c2[j]; ++k; }
#pragma unroll
    for (int j = 0; j < 8; ++j)
      if (c3[j] <= T) { srv[w][k] = c3[j]; ++k; }
    asm volatile("s_waitcnt lgkmcnt(0)" ::: "memory");
    unsigned long long s0 = srv[w][2 * l];
    unsigned long long s1 = srv[w][2 * l + 1];
    bitonic128(s0, s1, l);
    if (l < 24) {
      int2 o = make_int2((int)(unsigned int)s0, (int)(unsigned int)s1);
      *reinterpret_cast<int2*>(&idx_out[(size_t)bn * NB_KT + 2 * l]) = o;
    }
  } else {
    // ---- fallback: proven serial extraction (lists are untouched) ----
#define POP(A)                                                \
  {                                                           \
    A[0] = A[1]; A[1] = A[2]; A[2] = A[3]; A[3] = A[4];       \
    A[4] = A[5]; A[5] = A[6]; A[6] = A[7]; A[7] = ~0ULL;      \
  }
    unsigned long long lm;
    {
      unsigned long long a = u64min(c0[0], c1[0]);
      unsigned long long b2 = u64min(c2[0], c3[0]);
      lm = u64min(a, b2);
    }
    unsigned int my_out = 0;
    for (int r = 0; r < NB_KT; ++r) {
      unsigned long long g = lm;
      DPP_MIN64(g, 0xB1)
      DPP_MIN64(g, 0x4E)
      DPP_MIN64(g, 0x141)
      DPP_MIN64(g, 0x140)
      {
        unsigned long long o = __shfl_xor(g, 16);
        if (o < g) g = o;
      }
      {
        unsigned long long o = __shfl_xor(g, 32);
        if (o < g) g = o;
      }
      if (l == r) my_out = (unsigned int)g;
      if (lm == g) {
        if (c0[0] == g) { POP(c0) }
        else if (c1[0] == g) { POP(c1) }
        else if (c2[0] == g) { POP(c2) }
        else { POP(c3) }
        unsigned long long a = u64min(c0[0], c1[0]);
        unsigned long long b2 = u64min(c2[0], c3[0]);
        lm = u64min(a, b2);
      }
    }
#undef POP
    if (l < NB_KT) idx_out[(size_t)bn * NB_KT + l] = (int)my_out;
  }
}

// ---------------------------------------------------------------------------
// main fused kernel: 4 waves/block, 2 points/wave (8 points/block), grid 2048
// -> 8 blocks/CU, 32 waves/CU occupancy cap (was 16). lane layout:
// h_l = l>>4 (head), cg = l&15; lane owns channels {4cg..4cg+3, 64+4cg..+3}.
// Neighbor rows loaded directly global->reg. All LDS wave-private, no barriers.
// ---------------------------------------------------------------------------
__global__ __launch_bounds__(256) void main_kernel(
    const float* __restrict__ pcd,
    const float* __restrict__ Wq, const float* __restrict__ bq,
    const float* __restrict__ bk,
    const float* __restrict__ Wv, const float* __restrict__ bv,
    const float* __restrict__ wkT,
    const int* __restrict__ nbr_idx,
    float* __restrict__ out) {
  __shared__ __align__(16) float self_lds[8][128];        // 4 KB
  __shared__ float q_lds[8][132];                         // 4.1 KB
  __shared__ float qbk_lds[8][12];                        // 384 B

  const int t = threadIdx.x;
  const int w = t >> 6, l = t & 63;
  const int h_l = l >> 4, cg = l & 15;
  const int ws = w * 2;                     // wave's slot base (2 points)
  const int pt_base = blockIdx.x * 8 + ws;
  const float* pcd_b = pcd + (size_t)((blockIdx.x * 8) >> 11) * NB_N * 128;

  // ---- stage self rows (wave-private slots) ----
#pragma unroll
  for (int p = 0; p < 2; ++p) {
    float2 s = reinterpret_cast<const float2*>(pcd + (size_t)(pt_base + p) * 128)[l];
    reinterpret_cast<float2*>(&self_lds[ws + p][0])[l] = s;
  }

  // ---- q,v matvec: lane owns output cols 2l, 2l+1 for both points ----
  float qa[2] = {0, 0}, qb[2] = {0, 0};
  float va[2] = {0, 0}, vb[2] = {0, 0};
#pragma unroll 4
  for (int c = 0; c < 128; ++c) {
    float2 wq = reinterpret_cast<const float2*>(Wq + c * 128)[l];
    float2 wv = reinterpret_cast<const float2*>(Wv + c * 128)[l];
#pragma unroll
    for (int p = 0; p < 2; ++p) {
      float x = self_lds[ws + p][c];
      qa[p] = fmaf(wq.x, x, qa[p]); qb[p] = fmaf(wq.y, x, qb[p]);
      va[p] = fmaf(wv.x, x, va[p]); vb[p] = fmaf(wv.y, x, vb[p]);
    }
  }
  {
    float2 bqv = reinterpret_cast<const float2*>(bq)[l];
    float2 bvv = reinterpret_cast<const float2*>(bv)[l];
#pragma unroll
    for (int p = 0; p < 2; ++p) {
      qa[p] += bqv.x; qb[p] += bqv.y; va[p] += bvv.x; vb[p] += bvv.y;
    }
  }
#pragma unroll
  for (int p = 0; p < 2; ++p) {
    q_lds[ws + p][h_l * 33 + 2 * cg] = qa[p];
    q_lds[ws + p][h_l * 33 + 2 * cg + 1] = qb[p];
  }
  // qbk[p][i][h] = q[h,:] . bk[i][h*32:...]  (wave-private)
  if (l < 24) {
    int p = l / 12, g = l % 12;
    int i = g >> 2, h = g & 3;
    const float* qp = &q_lds[ws + p][h * 33];
    const float* bkp = bk + i * 128 + h * 32;
    float s = 0.f;
#pragma unroll 8
    for (int d = 0; d < 32; ++d) s = fmaf(qp[d], bkp[d], s);
    qbk_lds[ws + p][g] = s;
  }

  int nidx[2];
#pragma unroll
  for (int p = 0; p < 2; ++p)
    nidx[p] = (l < 48) ? nbr_idx[(size_t)(pt_base + p) * NB_KT + l] : 0;

  float am[2] = {0, 0};

#pragma unroll
  for (int i = 0; i < 3; ++i) {
    // ---- u[p][t]: channel 4cg+t (t<4), 64+4cg+(t-4) (t>=4) ----
    float u[2][8];
#pragma unroll
    for (int p = 0; p < 2; ++p)
#pragma unroll
      for (int k = 0; k < 8; ++k) u[p][k] = 0.f;
    {
      const float* wrow = wkT + i * 16384 + (h_l * 32) * 128 + 4 * cg;
#pragma unroll 4
      for (int d = 0; d < 32; ++d) {
        float4 wa = *reinterpret_cast<const float4*>(wrow + d * 128);
        float4 wb = *reinterpret_cast<const float4*>(wrow + d * 128 + 64);
        float qv[2];
#pragma unroll
        for (int p = 0; p < 2; ++p) qv[p] = q_lds[ws + p][h_l * 33 + d];
#pragma unroll
        for (int p = 0; p < 2; ++p) {
          u[p][0] = fmaf(wa.x, qv[p], u[p][0]);
          u[p][1] = fmaf(wa.y, qv[p], u[p][1]);
          u[p][2] = fmaf(wa.z, qv[p], u[p][2]);
          u[p][3] = fmaf(wa.w, qv[p], u[p][3]);
          u[p][4] = fmaf(wb.x, qv[p], u[p][4]);
          u[p][5] = fmaf(wb.y, qv[p], u[p][5]);
          u[p][6] = fmaf(wb.z, qv[p], u[p][6]);
          u[p][7] = fmaf(wb.w, qv[p], u[p][7]);
        }
      }
    }
    // ---- base[p] = qbk[p][i][h_l] - sum_c self[c]*u[c] ----
    float base[2];
#pragma unroll
    for (int p = 0; p < 2; ++p) {
      const float4* sp = reinterpret_cast<const float4*>(&self_lds[ws + p][4 * cg]);
      float4 sA = sp[0];
      float4 sB = sp[16];   // +64 floats
      float sd;
      sd = sA.x * u[p][0];
      sd = fmaf(sA.y, u[p][1], sd);
      sd = fmaf(sA.z, u[p][2], sd);
      sd = fmaf(sA.w, u[p][3], sd);
      sd = fmaf(sB.x, u[p][4], sd);
      sd = fmaf(sB.y, u[p][5], sd);
      sd = fmaf(sB.z, u[p][6], sd);
      sd = fmaf(sB.w, u[p][7], sd);
      sd = sum16(sd);
      base[p] = qbk_lds[ws + p][i * 4 + h_l] - sd;
    }
    // ---- logits: 16 neighbor rows per point, direct global->reg ----
#pragma unroll
    for (int p = 0; p < 2; ++p) {
      float myl = 0.f;
#pragma unroll
      for (int j = 0; j < 16; ++j) {
        int nb = __builtin_amdgcn_readlane(nidx[p], i * 16 + j);  // SGPR base
        const float* rowp = pcd_b + (size_t)(unsigned)nb * 128 + 4 * cg;
        float4 nA = *reinterpret_cast<const float4*>(rowp);
        float4 nB = *reinterpret_cast<const float4*>(rowp + 64);
        float pd;
        pd = nA.x * u[p][0];
        pd = fmaf(nA.y, u[p][1], pd);
        pd = fmaf(nA.z, u[p][2], pd);
        pd = fmaf(nA.w, u[p][3], pd);
        pd = fmaf(nB.x, u[p][4], pd);
        pd = fmaf(nB.y, u[p][5], pd);
        pd = fmaf(nB.z, u[p][6], pd);
        pd = fmaf(nB.w, u[p][7], pd);
        pd = sum16(pd);
        float lg = (pd + base[p]) * INV_SQRT_D;
        if (cg == j) myl = lg;
      }
      // softmax over the 16 lanes of this head group (all-VALU DPP)
      float m = max16(myl);
      float e = expf(myl - m);
      float swl = e * myl;
      float se = sum16(e);
      swl = sum16(swl);
      am[p] += swl / se;
    }
  }

  // ---- epilogue: out[pt_p, 2l+{0,1}] = attn[h_l] * v ----
#pragma unroll
  for (int p = 0; p < 2; ++p) {
    float2 o = make_float2(am[p] * va[p], am[p] * vb[p]);
    reinterpret_cast<float2*>(out + (size_t)(pt_base + p) * 128)[l] = o;
  }
}

// ---------------------------------------------------------------------------
extern "C" void kernel_launch(void* const* d_in, const int* in_sizes, int n_in,
                              void* d_out, int out_size, void* d_ws, size_t ws_size,
                              hipStream_t stream) {
  const float* pcd   = (const float*)d_in[0];
  const float* coord = (const float*)d_in[1];
  // d_in[2] = K (scalar int, fixed 16 — hardcoded)
  const float* Wq = (const float*)d_in[3];
  const float* bq = (const float*)d_in[4];
  const float* Wk = (const float*)d_in[5];
  const float* bk = (const float*)d_in[6];
  const float* Wv = (const float*)d_in[7];
  const float* bv = (const float*)d_in[8];
  float* out = (float*)d_out;

  // workspace layout
  int*   idx_ws = (int*)d_ws;                                   // 16384*48*4 = 3,145,728 B
  float* sq_ws  = (float*)((char*)d_ws + 3145728);              // 65,536 B
  float* wkT_ws = (float*)((char*)d_ws + 3211264);              // 196,608 B

  prep_kernel<<<192, 256, 0, stream>>>(coord, Wk, sq_ws, wkT_ws);
  topk3_kernel<<<NB_B * NB_N / 4, 256, 0, stream>>>(coord, sq_ws, idx_ws);
  main_kernel<<<NB_B * NB_N / 8, 256, 0, stream>>>(pcd, Wq, bq, bk, Wv, bv,
                                                   wkT_ws, idx_ws, out);
}